// Round 6
// baseline (275.741 us; speedup 1.0000x reference)
//
#include <hip/hip_runtime.h>

#define N_NODES 40000
#define N_EDGES 640000
#define N_GRAPHS 64

typedef unsigned short u16;
typedef unsigned int u32;
typedef __attribute__((ext_vector_type(8))) short bf16x8;
typedef __attribute__((ext_vector_type(4))) float f32x4;

static inline int cdiv(long long a, int b) { return (int)((a + b - 1) / b); }

// ---------------- bf16 helpers (bf16 = top 16 bits of fp32) ----------------
__device__ __forceinline__ u16 f2bf(float f) {
    u32 u = __float_as_uint(f);
    u32 r = (u + 0x7fffu + ((u >> 16) & 1u)) >> 16;  // round-to-nearest-even
    return (u16)r;
}
__device__ __forceinline__ u32 packpair(float a, float b) {
    return (u32)f2bf(a) | ((u32)f2bf(b) << 16);
}
__device__ __forceinline__ void unpack8(uint4 q, float* o) {
    o[0] = __uint_as_float(q.x << 16); o[1] = __uint_as_float(q.x & 0xffff0000u);
    o[2] = __uint_as_float(q.y << 16); o[3] = __uint_as_float(q.y & 0xffff0000u);
    o[4] = __uint_as_float(q.z << 16); o[5] = __uint_as_float(q.z & 0xffff0000u);
    o[6] = __uint_as_float(q.w << 16); o[7] = __uint_as_float(q.w & 0xffff0000u);
}

// ---------------------------- CSR build ------------------------------------
__global__ __launch_bounds__(256) void hist_kernel(const int* __restrict__ dst,
                                                   int* __restrict__ deg) {
    int e = blockIdx.x * 256 + threadIdx.x;
    if (e < N_EDGES) atomicAdd(&deg[dst[e]], 1);
}

__global__ __launch_bounds__(1024) void scan_part(const int* __restrict__ deg,
                                                  int* __restrict__ row_start,
                                                  int* __restrict__ bsum) {
    __shared__ int wtot[16], woff[16];
    int tid = threadIdx.x;
    int i = blockIdx.x * 1024 + tid;
    int v = (i < N_NODES) ? deg[i] : 0;
    int lane = tid & 63, wid = tid >> 6;
    int inc = v;
    #pragma unroll
    for (int off = 1; off < 64; off <<= 1) {
        int y = __shfl_up(inc, off, 64);
        if (lane >= off) inc += y;
    }
    if (lane == 63) wtot[wid] = inc;
    __syncthreads();
    if (tid < 16) {
        int b = wtot[tid];
        #pragma unroll
        for (int off = 1; off < 16; off <<= 1) {
            int y = __shfl_up(b, off, 16);
            if ((tid & 15) >= off) b += y;
        }
        woff[tid] = b - wtot[tid];
        if (tid == 15) bsum[blockIdx.x] = b;
    }
    __syncthreads();
    if (i <= N_NODES) row_start[i] = woff[wid] + inc - v;
}

__global__ __launch_bounds__(1024) void scan_add(int* __restrict__ row_start,
                                                 const int* __restrict__ bsum,
                                                 int* __restrict__ cursor) {
    __shared__ int sbase;
    int tid = threadIdx.x;
    if (tid < 64) {
        int b = (tid < blockIdx.x) ? bsum[tid] : 0;
        #pragma unroll
        for (int off = 32; off; off >>= 1) b += __shfl_xor(b, off, 64);
        if (tid == 0) sbase = b;
    }
    __syncthreads();
    int i = blockIdx.x * 1024 + tid;
    if (i <= N_NODES) {
        int v = row_start[i] + sbase;
        row_start[i] = v;
        if (i < N_NODES) cursor[i] = v;
    }
}

__global__ __launch_bounds__(256) void scatter_kernel(const int* __restrict__ src,
                                                      const int* __restrict__ dst,
                                                      const float* __restrict__ ew,
                                                      int* __restrict__ cursor,
                                                      int2* __restrict__ csr_pair) {
    int e = blockIdx.x * 256 + threadIdx.x;
    if (e >= N_EDGES) return;
    int pos = atomicAdd(&cursor[dst[e]], 1);
    int2 q;
    q.x = src[e];
    q.y = __float_as_int(ew[e]);
    csr_pair[pos] = q;
}

// ---------------- weight packing into MFMA B-fragment layout ---------------
// B_pack[nt][ks][lane][j] = bf16( Wstk[ks*32 + (lane>>4)*8 + j][nt*16 + (lane&15)] )
// Wstk = [w_rel (Kreal/2 rows); w_root (Kreal/2 rows); zeros up to KS*32].
__device__ __forceinline__ void pack_one(int idx, int KS, int Kreal, int FOUT,
                                         const float* __restrict__ wrel,
                                         const float* __restrict__ wroot,
                                         u16* __restrict__ out) {
    int j = idx & 7;
    int lane = (idx >> 3) & 63;
    int rest = idx >> 9;
    int nt = rest / KS, ks = rest - nt * KS;
    int k = ks * 32 + (lane >> 4) * 8 + j;
    int col = nt * 16 + (lane & 15);
    float v = 0.f;
    if (k < Kreal / 2) v = wrel[k * FOUT + col];
    else if (k < Kreal) v = wroot[(k - Kreal / 2) * FOUT + col];
    out[idx] = f2bf(v);
}

__global__ __launch_bounds__(256) void pack_weights(
        const float* __restrict__ wr2, const float* __restrict__ wo2,
        const float* __restrict__ wr3, const float* __restrict__ wo3,
        const float* __restrict__ wr4, const float* __restrict__ wo4,
        const float* __restrict__ wr5, const float* __restrict__ wo5,
        u16* __restrict__ p2, u16* __restrict__ p3,
        u16* __restrict__ p4, u16* __restrict__ p5) {
    int tid = blockIdx.x * 256 + threadIdx.x;
    if (tid < 512)         pack_one(tid,         1,  16,  16,  wr2, wo2, p2);
    else if (tid < 1536)   pack_one(tid - 512,   1,  32,  32,  wr3, wo3, p3);
    else if (tid < 5632)   pack_one(tid - 1536,  2,  64,  64,  wr4, wo4, p4);
    else if (tid < 22016)  pack_one(tid - 5632,  4, 128, 128,  wr5, wo5, p5);
}

// ---------------- x -> bf16[8] rows (feat 7 zero-padded) -------------------
__global__ __launch_bounds__(256) void convert_x(const float* __restrict__ x,
                                                 u16* __restrict__ xbf) {
    int n = blockIdx.x * 256 + threadIdx.x;
    if (n >= N_NODES) return;
    float v[8];
    #pragma unroll
    for (int i = 0; i < 7; ++i) v[i] = x[n * 7 + i];
    v[7] = 0.f;
    uint4 q;
    q.x = packpair(v[0], v[1]); q.y = packpair(v[2], v[3]);
    q.z = packpair(v[4], v[5]); q.w = packpair(v[6], v[7]);
    *(uint4*)(xbf + (long long)n * 8) = q;
}

// ---------------- bf16 gather (used for layer 1 only now) ------------------
template<int LOGF, int SLOG, int IN_STRIDE, int IN_OFF, int OUT_STRIDE, int OUT_OFF>
__global__ __launch_bounds__(256) void gather_bf16(const u16* __restrict__ hbuf,
                                                   const int* __restrict__ rs,
                                                   const int2* __restrict__ pair,
                                                   u16* __restrict__ obuf) {
    const int S = 1 << SLOG;
    long long tid = (long long)blockIdx.x * 256 + threadIdx.x;
    int n = (int)(tid >> (LOGF + SLOG));
    if (n >= N_NODES) return;
    int sub = (int)(tid & ((1 << (LOGF + SLOG)) - 1));
    int c = sub & ((1 << LOGF) - 1);
    int half = sub >> LOGF;
    const u16* base = hbuf + IN_OFF + c * 8;
    int beg = rs[n], end = rs[n + 1];
    float acc[8] = {0.f, 0.f, 0.f, 0.f, 0.f, 0.f, 0.f, 0.f};
    int p = beg + half;
    int s = 0; float w = 0.f;
    if (p < end) { int2 q = pair[p]; s = q.x; w = __int_as_float(q.y); }
    while (p < end) {
        uint4 rq = *(const uint4*)(base + (long long)s * IN_STRIDE);
        float wc = w;
        int pn = p + S;
        if (pn < end) { int2 q = pair[pn]; s = q.x; w = __int_as_float(q.y); }
        float tv[8];
        unpack8(rq, tv);
        #pragma unroll
        for (int j = 0; j < 8; ++j) acc[j] = fmaf(wc, tv[j], acc[j]);
        p = pn;
    }
    #pragma unroll
    for (int d = (1 << LOGF); d < (1 << (LOGF + SLOG)); d <<= 1) {
        #pragma unroll
        for (int j = 0; j < 8; ++j) acc[j] += __shfl_xor(acc[j], d, 64);
    }
    if (half == 0) {
        uint4 o;
        o.x = packpair(acc[0], acc[1]); o.y = packpair(acc[2], acc[3]);
        o.z = packpair(acc[4], acc[5]); o.w = packpair(acc[6], acc[7]);
        *(uint4*)(obuf + (long long)n * OUT_STRIDE + OUT_OFF + c * 8) = o;
    }
}

// ---------------- layer-1 node update (bf16 in, bf16 out) ------------------
__global__ __launch_bounds__(256) void node1b(const u16* __restrict__ agg1,
                                              const u16* __restrict__ xbf,
                                              const float* __restrict__ wr,
                                              const float* __restrict__ br,
                                              const float* __restrict__ wo,
                                              u16* __restrict__ h2) {
    __shared__ float swr[56], swo[56], sb[8];
    if (threadIdx.x < 56) { swr[threadIdx.x] = wr[threadIdx.x]; swo[threadIdx.x] = wo[threadIdx.x]; }
    if (threadIdx.x < 8) sb[threadIdx.x] = br[threadIdx.x];
    __syncthreads();
    int n = blockIdx.x * 256 + threadIdx.x;
    if (n >= N_NODES) return;
    float a[8], h[8];
    uint4 qa = *(const uint4*)(agg1 + (long long)n * 8);
    uint4 qh = *(const uint4*)(xbf + (long long)n * 8);
    unpack8(qa, a);
    unpack8(qh, h);
    float o[8];
    #pragma unroll
    for (int j = 0; j < 8; ++j) {
        float s = sb[j];
        #pragma unroll
        for (int i = 0; i < 7; ++i) s = fmaf(a[i], swr[i * 8 + j], fmaf(h[i], swo[i * 8 + j], s));
        o[j] = s;
    }
    uint4 q;
    q.x = packpair(o[0], o[1]); q.y = packpair(o[2], o[3]);
    q.z = packpair(o[4], o[5]); q.w = packpair(o[6], o[7]);
    *(uint4*)(h2 + (long long)n * 8) = q;
}

// ---------------- fused gather + MFMA node update (layers 2..5) ------------
// Block = 256 threads = one 16-node tile. Gather agg into LDS [16][K+8]
// (agg at k<FIN, staged hin at FIN<=k<2FIN, zeros beyond), then MFMA.
template<int LOGC, int FOUT, bool POOL>
__global__ __launch_bounds__(256) void fused_layer(const u16* __restrict__ hin,
                                                   const int* __restrict__ rs,
                                                   const int2* __restrict__ pair,
                                                   const u16* __restrict__ bpack,
                                                   const float* __restrict__ b_rel,
                                                   u16* __restrict__ hout,
                                                   const int* __restrict__ batch,
                                                   float* __restrict__ pooled) {
    constexpr int FIN = 8 << LOGC;
    constexpr int KREAL = 2 * FIN;
    constexpr int K = (KREAL < 32) ? 32 : KREAL;
    constexpr int KS = K / 32;
    constexpr int NT = FOUT / 16;
    constexpr int NTW = (NT + 3) / 4;   // n-tiles per wave
    constexpr int LDK = K + 8;          // +16B pad: MFMA A-reads 2-way max aliasing
    constexpr int CHUNKS = 1 << LOGC;   // 8-feat chunks per node
    constexpr int SPLIT = 64 >> LOGC;   // edge-split ways

    __shared__ u16 lds[16][LDK];

    int tid = threadIdx.x;
    int wave = tid >> 6;
    int lane = tid & 63;
    int node0 = blockIdx.x * 16;

    // zero the K-pad region (only when KREAL < K, i.e. layer 2)
    if constexpr (KREAL < K) {
        for (int i = tid; i < 16 * (K - KREAL); i += 256) {
            int r = i / (K - KREAL), cc = i % (K - KREAL);
            lds[r][KREAL + cc] = 0;
        }
    }
    // stage own 16 nodes' hin into lds[:][FIN..2FIN)
    {
        constexpr int CH = FIN / 8;
        for (int i = tid; i < 16 * CH; i += 256) {
            int r = i / CH, cc = i % CH;
            uint4 v = *(const uint4*)(hin + (long long)(node0 + r) * FIN + cc * 8);
            *(uint4*)&lds[r][FIN + cc * 8] = v;
        }
    }

    // gather phase: 4 rounds, wave w handles node node0 + rnd*4 + w
    int c = lane & (CHUNKS - 1);
    int half = lane >> LOGC;
    #pragma unroll
    for (int rnd = 0; rnd < 4; ++rnd) {
        int nl = rnd * 4 + wave;
        int n = node0 + nl;
        int beg = rs[n], end = rs[n + 1];
        float acc[8] = {0.f, 0.f, 0.f, 0.f, 0.f, 0.f, 0.f, 0.f};
        int p = beg + half;
        int s = 0; float w = 0.f;
        if (p < end) { int2 q = pair[p]; s = q.x; w = __int_as_float(q.y); }
        while (p < end) {
            uint4 rq = *(const uint4*)(hin + (long long)s * FIN + c * 8);
            float wc = w;
            int pn = p + SPLIT;
            if (pn < end) { int2 q = pair[pn]; s = q.x; w = __int_as_float(q.y); }
            float tv[8];
            unpack8(rq, tv);
            #pragma unroll
            for (int j = 0; j < 8; ++j) acc[j] = fmaf(wc, tv[j], acc[j]);
            p = pn;
        }
        #pragma unroll
        for (int d = CHUNKS; d < 64; d <<= 1) {
            #pragma unroll
            for (int j = 0; j < 8; ++j) acc[j] += __shfl_xor(acc[j], d, 64);
        }
        if (half == 0) {
            uint4 o;
            o.x = packpair(acc[0], acc[1]); o.y = packpair(acc[2], acc[3]);
            o.z = packpair(acc[4], acc[5]); o.w = packpair(acc[6], acc[7]);
            *(uint4*)&lds[nl][c * 8] = o;
        }
    }
    __syncthreads();

    // MFMA phase: wave w computes n-tiles [wave*NTW, wave*NTW+NTW)
    int ntbase = wave * NTW;
    if (ntbase >= NT) return;   // no barriers after this point

    int colc = lane & 15;
    int kg = (lane >> 4) * 8;

    f32x4 acc[NTW];
    #pragma unroll
    for (int t = 0; t < NTW; ++t) {
        float bv = b_rel[(ntbase + t) * 16 + colc];
        acc[t] = (f32x4){bv, bv, bv, bv};
    }

    #pragma unroll
    for (int ks = 0; ks < KS; ++ks) {
        bf16x8 af = *(const bf16x8*)&lds[colc][kg + ks * 32];
        #pragma unroll
        for (int t = 0; t < NTW; ++t) {
            int ntg = ntbase + t;
            bf16x8 bf = *(const bf16x8*)(bpack + (((ntg * KS + ks) << 6) + lane) * 8);
            acc[t] = __builtin_amdgcn_mfma_f32_16x16x32_bf16(af, bf, acc[t], 0, 0, 0);
        }
    }

    int row0 = (lane >> 4) * 4;  // local D-rows row0..row0+3
    if constexpr (!POOL) {
        #pragma unroll
        for (int t = 0; t < NTW; ++t)
            #pragma unroll
            for (int r = 0; r < 4; ++r)
                hout[(long long)(node0 + row0 + r) * FOUT + (ntbase + t) * 16 + colc] =
                    f2bf(acc[t][r]);
    } else {
        int b_first = batch[node0];
        int b_last = batch[node0 + 15];
        if (b_first == b_last) {
            #pragma unroll
            for (int t = 0; t < NTW; ++t) {
                float s2 = acc[t][0] + acc[t][1] + acc[t][2] + acc[t][3];
                s2 += __shfl_xor(s2, 16, 64);
                s2 += __shfl_xor(s2, 32, 64);
                if (lane < 16) atomicAdd(&pooled[b_first * FOUT + (ntbase + t) * 16 + colc], s2);
            }
        } else {
            #pragma unroll
            for (int r = 0; r < 4; ++r) {
                int g = batch[node0 + row0 + r];
                #pragma unroll
                for (int t = 0; t < NTW; ++t)
                    atomicAdd(&pooled[g * FOUT + (ntbase + t) * 16 + colc], acc[t][r]);
            }
        }
    }
}

// ---------------- classifier -----------------------------------------------
__global__ void final_kernel(const float* __restrict__ pooled,
                             const float* __restrict__ w_lin,
                             const float* __restrict__ b_lin,
                             float* __restrict__ out) {
    int tid = threadIdx.x;
    int g = tid >> 1;
    int c = tid & 1;
    float acc = b_lin[c];
    #pragma unroll 8
    for (int fi = 0; fi < 128; ++fi)
        acc += pooled[g * 128 + fi] * w_lin[fi * 2 + c];
    out[g * 2 + c] = acc;
}

extern "C" void kernel_launch(void* const* d_in, const int* in_sizes, int n_in,
                              void* d_out, int out_size, void* d_ws, size_t ws_size,
                              hipStream_t stream) {
    const float* x     = (const float*)d_in[0];
    const int*   ei    = (const int*)d_in[1];
    const float* ea    = (const float*)d_in[2];
    const int*   batch = (const int*)d_in[3];
    const int* src = ei;
    const int* dst = ei + N_EDGES;

    const float* w_rel[5], *b_rel[5], *w_root[5];
    for (int i = 0; i < 5; ++i) {
        w_rel[i]  = (const float*)d_in[4 + 3 * i];
        b_rel[i]  = (const float*)d_in[5 + 3 * i];
        w_root[i] = (const float*)d_in[6 + 3 * i];
    }
    const float* w_lin = (const float*)d_in[19];
    const float* b_lin = (const float*)d_in[20];
    float* out = (float*)d_out;

    // ---- workspace layout (all sections 16B-aligned) ----
    u16*   xbf     = (u16*)d_ws;                       // 40000*8
    u16*   agg1    = xbf + 320000;                     // 40000*8
    u16*   h2      = agg1 + 320000;                    // 40000*8
    u16*   h3      = h2 + 320000;                      // 40000*16
    u16*   h4      = h3 + 640000;                      // 40000*32
    u16*   h5      = h4 + 1280000;                     // 40000*64
    float* pooled  = (float*)(h5 + 2560000);           // 64*128 fp32
    u16*   p2      = (u16*)(pooled + N_GRAPHS * 128);  // 512
    u16*   p3      = p2 + 512;                         // 1024
    u16*   p4      = p3 + 1024;                        // 4096
    u16*   p5      = p4 + 4096;                        // 16384
    int2*  csr_pair= (int2*)(p5 + 16384);              // 640000 (src, w)
    int*   deg     = (int*)(csr_pair + N_EDGES);       // 40000
    int*   rs      = deg + N_NODES;                    // 40001
    int*   cursor  = rs + N_NODES + 1;                 // 40000
    int*   bsum    = cursor + N_NODES;                 // 64

    const int BLK = 256;
    const int EB = cdiv(N_EDGES, BLK);

    // ---- input conversion + weight packing + CSR build ----
    convert_x<<<cdiv(N_NODES, BLK), BLK, 0, stream>>>(x, xbf);
    pack_weights<<<86, BLK, 0, stream>>>(w_rel[1], w_root[1], w_rel[2], w_root[2],
                                         w_rel[3], w_root[3], w_rel[4], w_root[4],
                                         p2, p3, p4, p5);
    hipMemsetAsync(deg, 0, (size_t)N_NODES * sizeof(int), stream);
    hipMemsetAsync(pooled, 0, (size_t)N_GRAPHS * 128 * sizeof(float), stream);
    hist_kernel<<<EB, BLK, 0, stream>>>(dst, deg);
    scan_part<<<40, 1024, 0, stream>>>(deg, rs, bsum);
    scan_add<<<40, 1024, 0, stream>>>(rs, bsum, cursor);
    scatter_kernel<<<EB, BLK, 0, stream>>>(src, dst, ea, cursor, csr_pair);

    // ---- layer 1: 7 -> 8 ----
    gather_bf16<0, 3, 8, 0, 8, 0><<<cdiv((long long)N_NODES * 8, BLK), BLK, 0, stream>>>(
        xbf, rs, csr_pair, agg1);
    node1b<<<cdiv(N_NODES, BLK), BLK, 0, stream>>>(agg1, xbf, w_rel[0], b_rel[0], w_root[0], h2);

    // ---- layers 2..5: fused gather + MFMA ----
    fused_layer<0, 16, false><<<2500, BLK, 0, stream>>>(h2, rs, csr_pair, p2, b_rel[1], h3, nullptr, nullptr);
    fused_layer<1, 32, false><<<2500, BLK, 0, stream>>>(h3, rs, csr_pair, p3, b_rel[2], h4, nullptr, nullptr);
    fused_layer<2, 64, false><<<2500, BLK, 0, stream>>>(h4, rs, csr_pair, p4, b_rel[3], h5, nullptr, nullptr);
    fused_layer<3, 128, true><<<2500, BLK, 0, stream>>>(h5, rs, csr_pair, p5, b_rel[4], nullptr, batch, pooled);

    // ---- classifier ----
    final_kernel<<<1, 128, 0, stream>>>(pooled, w_lin, b_lin, out);
}

// Round 7
// 240.831 us; speedup vs baseline: 1.1450x; 1.1450x over previous
//
#include <hip/hip_runtime.h>

#define N_NODES 40000
#define N_EDGES 640000
#define N_GRAPHS 64

typedef unsigned short u16;
typedef unsigned int u32;
typedef __attribute__((ext_vector_type(8))) short bf16x8;
typedef __attribute__((ext_vector_type(4))) float f32x4;

static inline int cdiv(long long a, int b) { return (int)((a + b - 1) / b); }

// ---------------- bf16 helpers (bf16 = top 16 bits of fp32) ----------------
__device__ __forceinline__ u16 f2bf(float f) {
    u32 u = __float_as_uint(f);
    u32 r = (u + 0x7fffu + ((u >> 16) & 1u)) >> 16;  // round-to-nearest-even
    return (u16)r;
}
__device__ __forceinline__ u32 packpair(float a, float b) {
    return (u32)f2bf(a) | ((u32)f2bf(b) << 16);
}
__device__ __forceinline__ void unpack8(uint4 q, float* o) {
    o[0] = __uint_as_float(q.x << 16); o[1] = __uint_as_float(q.x & 0xffff0000u);
    o[2] = __uint_as_float(q.y << 16); o[3] = __uint_as_float(q.y & 0xffff0000u);
    o[4] = __uint_as_float(q.z << 16); o[5] = __uint_as_float(q.z & 0xffff0000u);
    o[6] = __uint_as_float(q.w << 16); o[7] = __uint_as_float(q.w & 0xffff0000u);
}

// ---------------- weight packing into MFMA B-fragment layout ---------------
// B_pack[nt][ks][lane][j] = bf16( Wstk[ks*32 + (lane>>4)*8 + j][nt*16 + (lane&15)] )
// Wstk = [w_rel (Kreal/2 rows); w_root (Kreal/2 rows); zeros up to KS*32].
__device__ __forceinline__ void pack_one(int idx, int KS, int Kreal, int FOUT,
                                         const float* __restrict__ wrel,
                                         const float* __restrict__ wroot,
                                         u16* __restrict__ out) {
    int j = idx & 7;
    int lane = (idx >> 3) & 63;
    int rest = idx >> 9;
    int nt = rest / KS, ks = rest - nt * KS;
    int k = ks * 32 + (lane >> 4) * 8 + j;
    int col = nt * 16 + (lane & 15);
    float v = 0.f;
    if (k < Kreal / 2) v = wrel[k * FOUT + col];
    else if (k < Kreal) v = wroot[(k - Kreal / 2) * FOUT + col];
    out[idx] = f2bf(v);
}

// ---------------- prep: convert x, pack weights, zero deg & pooled ---------
__global__ __launch_bounds__(256) void prep_kernel(
        const float* __restrict__ x, u16* __restrict__ xbf,
        const float* __restrict__ wr2, const float* __restrict__ wo2,
        const float* __restrict__ wr3, const float* __restrict__ wo3,
        const float* __restrict__ wr4, const float* __restrict__ wo4,
        const float* __restrict__ wr5, const float* __restrict__ wo5,
        u16* __restrict__ p2, u16* __restrict__ p3,
        u16* __restrict__ p4, u16* __restrict__ p5,
        int* __restrict__ deg, float* __restrict__ pooled) {
    int tid = blockIdx.x * 256 + threadIdx.x;
    if (tid < 40000) {
        int n = tid;
        float v[8];
        #pragma unroll
        for (int i = 0; i < 7; ++i) v[i] = x[n * 7 + i];
        v[7] = 0.f;
        uint4 q;
        q.x = packpair(v[0], v[1]); q.y = packpair(v[2], v[3]);
        q.z = packpair(v[4], v[5]); q.w = packpair(v[6], v[7]);
        *(uint4*)(xbf + (long long)n * 8) = q;
    } else if (tid < 62016) {
        int t = tid - 40000;
        if (t < 512)        pack_one(t,        1,  16,  16,  wr2, wo2, p2);
        else if (t < 1536)  pack_one(t - 512,  1,  32,  32,  wr3, wo3, p3);
        else if (t < 5632)  pack_one(t - 1536, 2,  64,  64,  wr4, wo4, p4);
        else                pack_one(t - 5632, 4, 128, 128,  wr5, wo5, p5);
    } else if (tid < 102016) {
        deg[tid - 62016] = 0;
    } else if (tid < 110208) {
        pooled[tid - 102016] = 0.f;
    }
}

// ---------------------------- CSR build ------------------------------------
__global__ __launch_bounds__(256) void hist_kernel(const int* __restrict__ dst,
                                                   int* __restrict__ deg) {
    int e = blockIdx.x * 256 + threadIdx.x;
    if (e < N_EDGES) atomicAdd(&deg[dst[e]], 1);
}

__global__ __launch_bounds__(1024) void scan_part(const int* __restrict__ deg,
                                                  int* __restrict__ row_start,
                                                  int* __restrict__ bsum) {
    __shared__ int wtot[16], woff[16];
    int tid = threadIdx.x;
    int i = blockIdx.x * 1024 + tid;
    int v = (i < N_NODES) ? deg[i] : 0;
    int lane = tid & 63, wid = tid >> 6;
    int inc = v;
    #pragma unroll
    for (int off = 1; off < 64; off <<= 1) {
        int y = __shfl_up(inc, off, 64);
        if (lane >= off) inc += y;
    }
    if (lane == 63) wtot[wid] = inc;
    __syncthreads();
    if (tid < 16) {
        int b = wtot[tid];
        #pragma unroll
        for (int off = 1; off < 16; off <<= 1) {
            int y = __shfl_up(b, off, 16);
            if ((tid & 15) >= off) b += y;
        }
        woff[tid] = b - wtot[tid];
        if (tid == 15) bsum[blockIdx.x] = b;
    }
    __syncthreads();
    if (i <= N_NODES) row_start[i] = woff[wid] + inc - v;
}

__global__ __launch_bounds__(1024) void scan_add(int* __restrict__ row_start,
                                                 const int* __restrict__ bsum,
                                                 int* __restrict__ cursor) {
    __shared__ int sbase;
    int tid = threadIdx.x;
    if (tid < 64) {
        int b = (tid < blockIdx.x) ? bsum[tid] : 0;
        #pragma unroll
        for (int off = 32; off; off >>= 1) b += __shfl_xor(b, off, 64);
        if (tid == 0) sbase = b;
    }
    __syncthreads();
    int i = blockIdx.x * 1024 + tid;
    if (i <= N_NODES) {
        int v = row_start[i] + sbase;
        row_start[i] = v;
        if (i < N_NODES) cursor[i] = v;
    }
}

__global__ __launch_bounds__(256) void scatter_kernel(const int* __restrict__ src,
                                                      const int* __restrict__ dst,
                                                      const float* __restrict__ ew,
                                                      int* __restrict__ cursor,
                                                      int2* __restrict__ csr_pair) {
    int e = blockIdx.x * 256 + threadIdx.x;
    if (e >= N_EDGES) return;
    int pos = atomicAdd(&cursor[dst[e]], 1);
    int2 q;
    q.x = src[e];
    q.y = __float_as_int(ew[e]);
    csr_pair[pos] = q;
}

// ---------------- bf16 gather: agg[n][FIN] = sum_e w_e * hin[src_e][FIN] ---
// FIN = 8<<LOGF; (1<<(LOGF+SLOG)) lanes per node: CHUNKS x SPLIT.
template<int LOGF, int SLOG>
__global__ __launch_bounds__(256) void gather_bf16(const u16* __restrict__ hin,
                                                   const int* __restrict__ rs,
                                                   const int2* __restrict__ pair,
                                                   u16* __restrict__ agg) {
    constexpr int FIN = 8 << LOGF;
    constexpr int S = 1 << SLOG;
    long long tid = (long long)blockIdx.x * 256 + threadIdx.x;
    int n = (int)(tid >> (LOGF + SLOG));
    if (n >= N_NODES) return;
    int sub = (int)(tid & ((1 << (LOGF + SLOG)) - 1));
    int c = sub & ((1 << LOGF) - 1);
    int half = sub >> LOGF;
    const u16* base = hin + c * 8;
    int beg = rs[n], end = rs[n + 1];
    float acc[8] = {0.f, 0.f, 0.f, 0.f, 0.f, 0.f, 0.f, 0.f};
    int p = beg + half;
    int s = 0; float w = 0.f;
    if (p < end) { int2 q = pair[p]; s = q.x; w = __int_as_float(q.y); }
    while (p < end) {
        uint4 rq = *(const uint4*)(base + (long long)s * FIN);
        float wc = w;
        int pn = p + S;
        if (pn < end) { int2 q = pair[pn]; s = q.x; w = __int_as_float(q.y); }
        float tv[8];
        unpack8(rq, tv);
        #pragma unroll
        for (int j = 0; j < 8; ++j) acc[j] = fmaf(wc, tv[j], acc[j]);
        p = pn;
    }
    #pragma unroll
    for (int d = (1 << LOGF); d < (1 << (LOGF + SLOG)); d <<= 1) {
        #pragma unroll
        for (int j = 0; j < 8; ++j) acc[j] += __shfl_xor(acc[j], d, 64);
    }
    if (half == 0) {
        uint4 o;
        o.x = packpair(acc[0], acc[1]); o.y = packpair(acc[2], acc[3]);
        o.z = packpair(acc[4], acc[5]); o.w = packpair(acc[6], acc[7]);
        *(uint4*)(agg + (long long)n * FIN + c * 8) = o;
    }
}

// ---------------- layer-1 node update (bf16 in, bf16 out) ------------------
__global__ __launch_bounds__(256) void node1b(const u16* __restrict__ agg1,
                                              const u16* __restrict__ xbf,
                                              const float* __restrict__ wr,
                                              const float* __restrict__ br,
                                              const float* __restrict__ wo,
                                              u16* __restrict__ h2) {
    __shared__ float swr[56], swo[56], sb[8];
    if (threadIdx.x < 56) { swr[threadIdx.x] = wr[threadIdx.x]; swo[threadIdx.x] = wo[threadIdx.x]; }
    if (threadIdx.x < 8) sb[threadIdx.x] = br[threadIdx.x];
    __syncthreads();
    int n = blockIdx.x * 256 + threadIdx.x;
    if (n >= N_NODES) return;
    float a[8], h[8];
    uint4 qa = *(const uint4*)(agg1 + (long long)n * 8);
    uint4 qh = *(const uint4*)(xbf + (long long)n * 8);
    unpack8(qa, a);
    unpack8(qh, h);
    float o[8];
    #pragma unroll
    for (int j = 0; j < 8; ++j) {
        float s = sb[j];
        #pragma unroll
        for (int i = 0; i < 7; ++i) s = fmaf(a[i], swr[i * 8 + j], fmaf(h[i], swo[i * 8 + j], s));
        o[j] = s;
    }
    uint4 q;
    q.x = packpair(o[0], o[1]); q.y = packpair(o[2], o[3]);
    q.z = packpair(o[4], o[5]); q.w = packpair(o[6], o[7]);
    *(uint4*)(h2 + (long long)n * 8) = q;
}

// ---------------- MFMA node update: [agg|hin] @ [wrel;wroot] ---------------
// One wave per 16-node M-tile. A-frag row = lane&15, k = ks*32+(lane>>4)*8;
// k < FIN reads agg, FIN <= k < 2FIN reads hin, else zero (L2 pad).
// D mapping (m89-verified): col = lane&15, row = (lane>>4)*4 + r.
template<int FIN, int FOUT, bool POOL>
__global__ __launch_bounds__(64) void node_mfma(const u16* __restrict__ agg,
                                                const u16* __restrict__ hin,
                                                const u16* __restrict__ bpack,
                                                const float* __restrict__ b_rel,
                                                u16* __restrict__ hout,
                                                const int* __restrict__ batch,
                                                float* __restrict__ pooled) {
    constexpr int KREAL = 2 * FIN;
    constexpr int K = (KREAL < 32) ? 32 : KREAL;
    constexpr int KS = K / 32;
    constexpr int NT = FOUT / 16;
    int lane = threadIdx.x;
    int tile = blockIdx.x;               // 0..2499
    int col = lane & 15;
    int node_a = tile * 16 + col;        // A-frag row for this lane
    int kgrp = (lane >> 4) * 8;

    f32x4 acc[NT];
    #pragma unroll
    for (int nt = 0; nt < NT; ++nt) {
        float bv = b_rel[nt * 16 + col];
        acc[nt] = (f32x4){bv, bv, bv, bv};
    }

    #pragma unroll
    for (int ks = 0; ks < KS; ++ks) {
        int k0 = ks * 32 + kgrp;
        bf16x8 af;
        if (k0 < FIN)
            af = *(const bf16x8*)(agg + (long long)node_a * FIN + k0);
        else if (k0 < KREAL)
            af = *(const bf16x8*)(hin + (long long)node_a * FIN + (k0 - FIN));
        else
            af = (bf16x8)(short)0;
        #pragma unroll
        for (int nt = 0; nt < NT; ++nt) {
            bf16x8 bf = *(const bf16x8*)(bpack + (((nt * KS + ks) << 6) + lane) * 8);
            acc[nt] = __builtin_amdgcn_mfma_f32_16x16x32_bf16(af, bf, acc[nt], 0, 0, 0);
        }
    }

    int row0 = tile * 16 + (lane >> 4) * 4;  // this lane's 4 D-rows
    if constexpr (!POOL) {
        #pragma unroll
        for (int nt = 0; nt < NT; ++nt)
            #pragma unroll
            for (int r = 0; r < 4; ++r)
                hout[(long long)(row0 + r) * FOUT + nt * 16 + col] = f2bf(acc[nt][r]);
    } else {
        int b_first = batch[tile * 16];
        int b_last = batch[tile * 16 + 15];
        if (b_first == b_last) {
            // whole tile in one graph (common: sorted batch): reduce, 1 atomic/col
            #pragma unroll
            for (int nt = 0; nt < NT; ++nt) {
                float s = acc[nt][0] + acc[nt][1] + acc[nt][2] + acc[nt][3];
                s += __shfl_xor(s, 16, 64);
                s += __shfl_xor(s, 32, 64);
                if (lane < 16) atomicAdd(&pooled[b_first * FOUT + nt * 16 + col], s);
            }
        } else {
            #pragma unroll
            for (int r = 0; r < 4; ++r) {
                int g = batch[row0 + r];
                #pragma unroll
                for (int nt = 0; nt < NT; ++nt)
                    atomicAdd(&pooled[g * FOUT + nt * 16 + col], acc[nt][r]);
            }
        }
    }
}

// ---------------- classifier -----------------------------------------------
__global__ void final_kernel(const float* __restrict__ pooled,
                             const float* __restrict__ w_lin,
                             const float* __restrict__ b_lin,
                             float* __restrict__ out) {
    int tid = threadIdx.x;
    int g = tid >> 1;
    int c = tid & 1;
    float acc = b_lin[c];
    #pragma unroll 8
    for (int fi = 0; fi < 128; ++fi)
        acc += pooled[g * 128 + fi] * w_lin[fi * 2 + c];
    out[g * 2 + c] = acc;
}

extern "C" void kernel_launch(void* const* d_in, const int* in_sizes, int n_in,
                              void* d_out, int out_size, void* d_ws, size_t ws_size,
                              hipStream_t stream) {
    const float* x     = (const float*)d_in[0];
    const int*   ei    = (const int*)d_in[1];
    const float* ea    = (const float*)d_in[2];
    const int*   batch = (const int*)d_in[3];
    const int* src = ei;
    const int* dst = ei + N_EDGES;

    const float* w_rel[5], *b_rel[5], *w_root[5];
    for (int i = 0; i < 5; ++i) {
        w_rel[i]  = (const float*)d_in[4 + 3 * i];
        b_rel[i]  = (const float*)d_in[5 + 3 * i];
        w_root[i] = (const float*)d_in[6 + 3 * i];
    }
    const float* w_lin = (const float*)d_in[19];
    const float* b_lin = (const float*)d_in[20];
    float* out = (float*)d_out;

    // ---- workspace layout (all sections 16B-aligned) ----
    u16*   xbf     = (u16*)d_ws;                       // 40000*8
    u16*   agg     = xbf + 320000;                     // 40000*64 (shared, all layers)
    u16*   h2      = agg + 2560000;                    // 40000*8
    u16*   h3      = h2 + 320000;                      // 40000*16
    u16*   h4      = h3 + 640000;                      // 40000*32
    u16*   h5      = h4 + 1280000;                     // 40000*64
    float* pooled  = (float*)(h5 + 2560000);           // 64*128 fp32
    u16*   p2      = (u16*)(pooled + N_GRAPHS * 128);  // 512
    u16*   p3      = p2 + 512;                         // 1024
    u16*   p4      = p3 + 1024;                        // 4096
    u16*   p5      = p4 + 4096;                        // 16384
    int2*  csr_pair= (int2*)(p5 + 16384);              // 640000 (src, w)
    int*   deg     = (int*)(csr_pair + N_EDGES);       // 40000
    int*   rs      = deg + N_NODES;                    // 40001
    int*   cursor  = rs + N_NODES + 1;                 // 40000
    int*   bsum    = cursor + N_NODES;                 // 64

    const int BLK = 256;
    const int EB = cdiv(N_EDGES, BLK);

    // ---- prep (convert x, pack weights, zero deg/pooled) + CSR build ----
    prep_kernel<<<431, BLK, 0, stream>>>(x, xbf,
                                         w_rel[1], w_root[1], w_rel[2], w_root[2],
                                         w_rel[3], w_root[3], w_rel[4], w_root[4],
                                         p2, p3, p4, p5, deg, pooled);
    hist_kernel<<<EB, BLK, 0, stream>>>(dst, deg);
    scan_part<<<40, 1024, 0, stream>>>(deg, rs, bsum);
    scan_add<<<40, 1024, 0, stream>>>(rs, bsum, cursor);
    scatter_kernel<<<EB, BLK, 0, stream>>>(src, dst, ea, cursor, csr_pair);

    // ---- layer 1: 7 -> 8 (scalar-ish, tiny) ----
    gather_bf16<0, 3><<<cdiv((long long)N_NODES * 8, BLK), BLK, 0, stream>>>(
        xbf, rs, csr_pair, agg);
    node1b<<<cdiv(N_NODES, BLK), BLK, 0, stream>>>(agg, xbf, w_rel[0], b_rel[0], w_root[0], h2);

    // ---- layer 2: 8 -> 16 (MFMA, K padded to 32) ----
    gather_bf16<0, 3><<<cdiv((long long)N_NODES * 8, BLK), BLK, 0, stream>>>(
        h2, rs, csr_pair, agg);
    node_mfma<8, 16, false><<<2500, 64, 0, stream>>>(agg, h2, p2, b_rel[1], h3, nullptr, nullptr);

    // ---- layer 3: 16 -> 32 (MFMA) ----
    gather_bf16<1, 3><<<cdiv((long long)N_NODES * 16, BLK), BLK, 0, stream>>>(
        h3, rs, csr_pair, agg);
    node_mfma<16, 32, false><<<2500, 64, 0, stream>>>(agg, h3, p3, b_rel[2], h4, nullptr, nullptr);

    // ---- layer 4: 32 -> 64 (MFMA) ----
    gather_bf16<2, 3><<<cdiv((long long)N_NODES * 32, BLK), BLK, 0, stream>>>(
        h4, rs, csr_pair, agg);
    node_mfma<32, 64, false><<<2500, 64, 0, stream>>>(agg, h4, p4, b_rel[3], h5, nullptr, nullptr);

    // ---- layer 5: 64 -> 128 (MFMA, pooling fused) ----
    gather_bf16<3, 3><<<cdiv((long long)N_NODES * 64, BLK), BLK, 0, stream>>>(
        h5, rs, csr_pair, agg);
    node_mfma<64, 128, true><<<2500, 64, 0, stream>>>(agg, h5, p5, b_rel[4], nullptr, batch, pooled);

    // ---- classifier ----
    final_kernel<<<1, 128, 0, stream>>>(pooled, w_lin, b_lin, out);
}